// Round 8
// baseline (206.731 us; speedup 1.0000x reference)
//
#include <hip/hip_runtime.h>
#include <hip/hip_bf16.h>

// Problem: B=64, K=512 (KPLUS1=513), D=E=1024
// out[b,k] = softmax_k( sum_e tanh( (z[b,k,:]@Wz)[e] + (u[b,:]@Wu)[e] ) * bias[e] )
// R8: single-product fp16 GEMM (error budget verified in R7), BK=128 to
// halve barrier count and double MFMA per K-step. 128x128 tile, 4 waves,
// 64KB LDS (2 blocks/CU), pre-swizzled gload_lds staging (16-chunk XOR),
// uniform-bank ds_read_b128.

typedef __attribute__((ext_vector_type(8))) short short8;
typedef __attribute__((ext_vector_type(8))) _Float16 half8;
typedef __attribute__((ext_vector_type(4))) float f32x4;
typedef unsigned short ushort_t;

typedef const __attribute__((address_space(1))) void gvoid_t;
typedef __attribute__((address_space(3))) void lvoid_t;

__device__ __forceinline__ ushort_t f2bf(float f) {
    unsigned u = __float_as_uint(f);
    unsigned r = u + 0x7FFFu + ((u >> 16) & 1u);
    return (ushort_t)(r >> 16);
}
__device__ __forceinline__ float bf2f(ushort_t h) {
    return __uint_as_float(((unsigned)h) << 16);
}

// ---------------------------------------------------------------------------
// Kernel 0 (fast path): convert z = x[:,1:,:] to fp16 [32768][1024].
__global__ __launch_bounds__(256) void k_prep_z16(const float* __restrict__ x,
                                                  _Float16* __restrict__ z_h) {
    const int idx8 = blockIdx.x * 256 + threadIdx.x;
    const int m = idx8 >> 7;
    const int c = (idx8 & 127) * 8;
    const int b = m >> 9, k = m & 511;
    const float* src = x + ((size_t)(b * 513 + 1 + k) << 10) + c;
    const float4 v0 = *(const float4*)src;
    const float4 v1 = *(const float4*)(src + 4);
    float vv[8] = {v0.x, v0.y, v0.z, v0.w, v1.x, v1.y, v1.z, v1.w};
    half8 hv;
#pragma unroll
    for (int i = 0; i < 8; ++i) hv[i] = (_Float16)vv[i];
    *(half8*)(z_h + (size_t)m * 1024 + c) = hv;
}

// ---------------------------------------------------------------------------
// Kernel 1 (fast path): transpose Wz ([d][e], rows 0..1023) -> fp16 wzt [e][d].
__global__ void k_prep_w16(const float* __restrict__ w,
                           _Float16* __restrict__ wzt) {
    __shared__ _Float16 th[64][66];
    const int k0 = blockIdx.x * 64;
    const int n0 = blockIdx.y * 64;
    const int t = threadIdx.x;
    const int lr = t >> 6;
    const int lc = t & 63;
#pragma unroll
    for (int r = 0; r < 16; ++r) {
        int kk = r * 4 + lr;
        th[kk][lc] = (_Float16)w[(size_t)(k0 + kk) * 1024 + n0 + lc];
    }
    __syncthreads();
#pragma unroll
    for (int r = 0; r < 16; ++r) {
        int nn = r * 4 + lr;
        wzt[(size_t)(n0 + nn) * 1024 + k0 + lc] = th[lc][nn];
    }
}

// ---------------------------------------------------------------------------
// Kernel 2: hu[b][e] = sum_d u[b][d] * Wu[d][e], exact fp32.
__global__ void k_hu(const float* __restrict__ x,
                     const float* __restrict__ w,
                     float* __restrict__ hu) {
    __shared__ float us[1024];
    const int b = blockIdx.y;
    const int e = blockIdx.x * 256 + threadIdx.x;
    for (int i = threadIdx.x; i < 1024; i += 256)
        us[i] = x[(size_t)b * 513 * 1024 + i];
    __syncthreads();
    const float* wu = w + (size_t)1024 * 1024;
    float acc = 0.f;
#pragma unroll 8
    for (int d = 0; d < 1024; ++d)
        acc = fmaf(us[d], wu[(size_t)d * 1024 + e], acc);
    hu[b * 1024 + e] = acc;
}

// ---------------------------------------------------------------------------
// Kernel 3 (fast path): fp16 GEMM, BM=BN=128, BK=128, 4 waves 2x2 (each
// wave 64x64 = 4x4 frags of 16x16x32). 8 K-iterations. Staging via
// global_load_lds(16B) into linear LDS; swizzle via pre-permuted global
// source: logical chunk c of row r at physical slot c^(r&15); ds_read
// applies the same XOR -> uniform 8 accesses/bank (optimal b128).
__global__ __launch_bounds__(256) void k_gemm7(
        const _Float16* __restrict__ z_h,
        const _Float16* __restrict__ wzt,
        const float* __restrict__ hu,
        const float* __restrict__ bias,
        float* __restrict__ qp) {
    __shared__ __align__(16) _Float16 As[128 * 128];   // 32 KiB
    __shared__ __align__(16) _Float16 Bs[128 * 128];   // 32 KiB
    __shared__ float qred[2][2][64];

    const int t = threadIdx.x;
    const int mtile = blockIdx.x;   // 0..255
    const int ntile = blockIdx.y;   // 0..7
    const int wid = t >> 6;
    const int l = t & 63;
    const int wm = wid >> 1;
    const int wn = wid & 1;
    const int lr = l & 15;
    const int g = l >> 4;           // 0..3

    // ---- staging assignment: wave -> {A,B} x {half 0,1}; 16 x 1KiB calls.
    // call j covers rows 4j..4j+3 of the wave's 64-row half; lane l ->
    // row 4j+(l>>4), phys slot (l&15), logical src chunk slot^((4j+l>>4)&15)
    //   = (l&15) ^ (l>>4) ^ ((j&3)<<2).
    const int rl4 = l >> 4;            // 0..3
    const int cinv = (l & 15) ^ rl4;   // j-invariant part of logical chunk
    const int half = wid & 1;
    const _Float16* gbase;
    _Float16* ldsT;
    if (wid < 2) {
        gbase = z_h + (size_t)(mtile * 128 + half * 64 + rl4) * 1024;
        ldsT = As + half * 64 * 128;
    } else {
        gbase = wzt + (size_t)(ntile * 128 + half * 64 + rl4) * 1024;
        ldsT = Bs + half * 64 * 128;
    }

    f32x4 acc[4][4] = {};

    for (int k0 = 0; k0 < 1024; k0 += 128) {
        // ---- stage both 32KB tiles via direct global->LDS DMA ----
#pragma unroll
        for (int j = 0; j < 16; ++j) {
            const int cj = (cinv ^ ((j & 3) << 2)) * 8;
            __builtin_amdgcn_global_load_lds(
                (gvoid_t*)(gbase + k0 + j * 4096 + cj),
                (lvoid_t*)((char*)ldsT + j * 1024 + l * 16),
                16, 0, 0);
        }
        __syncthreads();   // compiler drains vmcnt before barrier

        // ---- compute: 4 k-subtiles of 32, 16 MFMA each ----
#pragma unroll
        for (int ks = 0; ks < 4; ++ks) {
            half8 ah[4], bh[4];
            const int so = ((ks * 4 + g) ^ lr) * 16;   // swizzled byte slot
#pragma unroll
            for (int i = 0; i < 4; ++i) {
                ah[i] = *(const half8*)((const char*)As + (wm * 64 + i * 16 + lr) * 256 + so);
                bh[i] = *(const half8*)((const char*)Bs + (wn * 64 + i * 16 + lr) * 256 + so);
            }
#pragma unroll
            for (int mi = 0; mi < 4; ++mi)
#pragma unroll
                for (int ni = 0; ni < 4; ++ni)
                    acc[mi][ni] = __builtin_amdgcn_mfma_f32_16x16x32_f16(
                        ah[mi], bh[ni], acc[mi][ni], 0, 0, 0);
        }
        __syncthreads();
    }

    // ---- epilogue: partial q over this wave's 64 e-cols ----
    const int lg = l >> 4;
    const int bbatch = mtile >> 2;   // 128 | 512 -> batch block-uniform
    float hu4[4], bias4[4];
#pragma unroll
    for (int ni = 0; ni < 4; ++ni) {
        int e = ntile * 128 + wn * 64 + ni * 16 + lr;
        hu4[ni] = hu[bbatch * 1024 + e];
        bias4[ni] = bias[e];
    }
#pragma unroll
    for (int mi = 0; mi < 4; ++mi) {
#pragma unroll
        for (int j = 0; j < 4; ++j) {
            float v = 0.f;
#pragma unroll
            for (int ni = 0; ni < 4; ++ni)
                v += tanhf(acc[mi][ni][j] + hu4[ni]) * bias4[ni];
            v += __shfl_xor(v, 1);
            v += __shfl_xor(v, 2);
            v += __shfl_xor(v, 4);
            v += __shfl_xor(v, 8);
            if (lr == 0)
                qred[wm][wn][mi * 16 + lg * 4 + j] = v;
        }
    }
    __syncthreads();
    if (t < 128) {
        const int wmr = t >> 6;
        const int rr = t & 63;
        float q = qred[wmr][0][rr] + qred[wmr][1][rr];
        qp[(size_t)ntile * 32768 + mtile * 128 + t] = q;
    }
}

// ---------------------------------------------------------------------------
// Fallback path (R2-verified): split-bf16, in-loop staging. Used only if
// ws_size is too small for the fast path.
__global__ void k_prep_w(const float* __restrict__ w,
                         ushort_t* __restrict__ wzt_hi,
                         ushort_t* __restrict__ wzt_lo) {
    __shared__ ushort_t th[64][66];
    __shared__ ushort_t tl[64][66];
    const int k0 = blockIdx.x * 64;
    const int n0 = blockIdx.y * 64;
    const int t = threadIdx.x;
    const int lr = t >> 6;
    const int lc = t & 63;
#pragma unroll
    for (int r = 0; r < 16; ++r) {
        int kk = r * 4 + lr;
        float f = w[(size_t)(k0 + kk) * 1024 + n0 + lc];
        ushort_t hi = f2bf(f);
        ushort_t lo = f2bf(f - bf2f(hi));
        th[kk][lc] = hi;
        tl[kk][lc] = lo;
    }
    __syncthreads();
#pragma unroll
    for (int r = 0; r < 16; ++r) {
        int nn = r * 4 + lr;
        wzt_hi[(size_t)(n0 + nn) * 1024 + k0 + lc] = th[lc][nn];
        wzt_lo[(size_t)(n0 + nn) * 1024 + k0 + lc] = tl[lc][nn];
    }
}

__global__ __launch_bounds__(256) void k_gemm(
        const float* __restrict__ x,
        const ushort_t* __restrict__ wzt_hi,
        const ushort_t* __restrict__ wzt_lo,
        const float* __restrict__ hu,
        const float* __restrict__ bias,
        float* __restrict__ qp) {
    __shared__ ushort_t As_hi[128][40];
    __shared__ ushort_t As_lo[128][40];
    __shared__ ushort_t Bs_hi[128][40];
    __shared__ ushort_t Bs_lo[128][40];
    __shared__ float qred[2][2][64];

    const int t = threadIdx.x;
    const int mtile = blockIdx.x;
    const int ntile = blockIdx.y;
    const int wid = t >> 6;
    const int l = t & 63;
    const int wm = wid >> 1;
    const int wn = wid & 1;

    f32x4 acc[4][4] = {};

    const int arow = t >> 3;
    const int acol = (t & 7) * 4;
    size_t abase[4];
#pragma unroll
    for (int it = 0; it < 4; ++it) {
        int m = mtile * 128 + arow + it * 32;
        int bb = m >> 9;
        int kk = m & 511;
        abase[it] = ((size_t)(bb * 513 + 1 + kk)) * 1024 + acol;
    }
    const int brow = t >> 2;
    const int bcol = (t & 3) * 8;
    const size_t bbase = (size_t)(ntile * 128 + brow) * 1024 + bcol;

    for (int k0 = 0; k0 < 1024; k0 += 32) {
#pragma unroll
        for (int it = 0; it < 4; ++it) {
            const float4 v = *(const float4*)(x + abase[it] + k0);
            ushort4 hv, lv;
            hv.x = f2bf(v.x); lv.x = f2bf(v.x - bf2f(hv.x));
            hv.y = f2bf(v.y); lv.y = f2bf(v.y - bf2f(hv.y));
            hv.z = f2bf(v.z); lv.z = f2bf(v.z - bf2f(hv.z));
            hv.w = f2bf(v.w); lv.w = f2bf(v.w - bf2f(hv.w));
            const int row = arow + it * 32;
            *(ushort4*)&As_hi[row][acol] = hv;
            *(ushort4*)&As_lo[row][acol] = lv;
        }
#pragma unroll
        for (int it = 0; it < 2; ++it) {
            const int row = brow + it * 64;
            const uint4 vh = *(const uint4*)(wzt_hi + bbase + (size_t)it * 64 * 1024 + k0);
            const uint4 vl = *(const uint4*)(wzt_lo + bbase + (size_t)it * 64 * 1024 + k0);
            *(uint4*)&Bs_hi[row][bcol] = vh;
            *(uint4*)&Bs_lo[row][bcol] = vl;
        }
        __syncthreads();

        const int lr = l & 15;
        const int lk = (l >> 4) * 8;
        short8 ah[4], al[4], bh[4], bl[4];
#pragma unroll
        for (int i = 0; i < 4; ++i) {
            ah[i] = *(const short8*)&As_hi[wm * 64 + i * 16 + lr][lk];
            al[i] = *(const short8*)&As_lo[wm * 64 + i * 16 + lr][lk];
            bh[i] = *(const short8*)&Bs_hi[wn * 64 + i * 16 + lr][lk];
            bl[i] = *(const short8*)&Bs_lo[wn * 64 + i * 16 + lr][lk];
        }
#pragma unroll
        for (int mi = 0; mi < 4; ++mi)
#pragma unroll
            for (int ni = 0; ni < 4; ++ni) {
                acc[mi][ni] = __builtin_amdgcn_mfma_f32_16x16x32_bf16(ah[mi], bh[ni], acc[mi][ni], 0, 0, 0);
                acc[mi][ni] = __builtin_amdgcn_mfma_f32_16x16x32_bf16(ah[mi], bl[ni], acc[mi][ni], 0, 0, 0);
                acc[mi][ni] = __builtin_amdgcn_mfma_f32_16x16x32_bf16(al[mi], bh[ni], acc[mi][ni], 0, 0, 0);
            }
        __syncthreads();
    }

    const int lr = l & 15;
    const int lg = l >> 4;
    const int bbatch = mtile >> 2;
    float hu4[4], bias4[4];
#pragma unroll
    for (int ni = 0; ni < 4; ++ni) {
        int e = ntile * 128 + wn * 64 + ni * 16 + lr;
        hu4[ni] = hu[bbatch * 1024 + e];
        bias4[ni] = bias[e];
    }
#pragma unroll
    for (int mi = 0; mi < 4; ++mi) {
#pragma unroll
        for (int j = 0; j < 4; ++j) {
            float v = 0.f;
#pragma unroll
            for (int ni = 0; ni < 4; ++ni)
                v += tanhf(acc[mi][ni][j] + hu4[ni]) * bias4[ni];
            v += __shfl_xor(v, 1);
            v += __shfl_xor(v, 2);
            v += __shfl_xor(v, 4);
            v += __shfl_xor(v, 8);
            if (lr == 0)
                qred[wm][wn][mi * 16 + lg * 4 + j] = v;
        }
    }
    __syncthreads();
    if (t < 128) {
        const int wmr = t >> 6;
        const int rr = t & 63;
        float q = qred[wmr][0][rr] + qred[wmr][1][rr];
        qp[(size_t)ntile * 32768 + mtile * 128 + t] = q;
    }
}

// ---------------------------------------------------------------------------
// Kernel 4: reduce partials over nt tiles + softmax over k (512) per batch.
__global__ void k_softmax(const float* __restrict__ qp, float* __restrict__ out,
                          int nt) {
    const int b = blockIdx.x;
    const int k = threadIdx.x;   // 512 threads
    float q = 0.f;
    for (int i = 0; i < nt; ++i)
        q += qp[(size_t)i * 32768 + b * 512 + k];

    __shared__ float redm[8];
    __shared__ float reds[8];
    const int wid = k >> 6;

    float m = q;
#pragma unroll
    for (int off = 32; off >= 1; off >>= 1)
        m = fmaxf(m, __shfl_xor(m, off));
    if ((k & 63) == 0) redm[wid] = m;
    __syncthreads();
    m = redm[0];
#pragma unroll
    for (int i = 1; i < 8; ++i) m = fmaxf(m, redm[i]);

    float p = expf(q - m);
    float s = p;
#pragma unroll
    for (int off = 32; off >= 1; off >>= 1)
        s += __shfl_xor(s, off);
    if ((k & 63) == 0) reds[wid] = s;
    __syncthreads();
    s = 0.f;
#pragma unroll
    for (int i = 0; i < 8; ++i) s += reds[i];

    out[b * 512 + k] = p / s;
}

// ---------------------------------------------------------------------------
extern "C" void kernel_launch(void* const* d_in, const int* in_sizes, int n_in,
                              void* d_out, int out_size, void* d_ws, size_t ws_size,
                              hipStream_t stream) {
    const float* x    = (const float*)d_in[0];   // (64, 513, 1024) f32
    const float* w    = (const float*)d_in[1];   // (2048, 1024) f32
    const float* bias = (const float*)d_in[2];   // (1024, 1) f32
    float* out = (float*)d_out;                  // (64, 512) f32

    char* ws = (char*)d_ws;
    const size_t ZN = (size_t)32768 * 1024;      // z elements

    // fast-path ws: z_h (64MB fp16) + wzt (2MB fp16) + hu (256KB) + qp (1MB)
    const size_t need = ZN * sizeof(_Float16)
                      + (size_t)1024 * 1024 * sizeof(_Float16)
                      + (size_t)64 * 1024 * sizeof(float)
                      + (size_t)8 * 32768 * sizeof(float);

    if (ws_size >= need) {
        _Float16* z_h = (_Float16*)ws;
        _Float16* wzt = z_h + ZN;
        float*    hu  = (float*)(wzt + (size_t)1024 * 1024);
        float*    qp  = hu + (size_t)64 * 1024;

        k_prep_z16<<<16384, 256, 0, stream>>>(x, z_h);
        k_prep_w16<<<dim3(16, 16), 256, 0, stream>>>(w, wzt);
        k_hu<<<dim3(4, 64), 256, 0, stream>>>(x, w, hu);
        k_gemm7<<<dim3(256, 8), 256, 0, stream>>>(z_h, wzt, hu, bias, qp);
        k_softmax<<<64, 512, 0, stream>>>(qp, out, 8);
    } else {
        ushort_t* wzt_hi = (ushort_t*)ws;
        ushort_t* wzt_lo = wzt_hi + (size_t)1024 * 1024;
        float* hu = (float*)(ws + (size_t)4 * 1024 * 1024);
        float* qp = hu + (size_t)64 * 1024;

        k_prep_w<<<dim3(16, 16), 256, 0, stream>>>(w, wzt_hi, wzt_lo);
        k_hu<<<dim3(4, 64), 256, 0, stream>>>(x, w, hu);
        k_gemm<<<dim3(256, 8), 256, 0, stream>>>(x, wzt_hi, wzt_lo, hu, bias, qp);
        k_softmax<<<64, 512, 0, stream>>>(qp, out, 8);
    }
}